// Round 4
// baseline (1997.026 us; speedup 1.0000x reference)
//
#include <hip/hip_runtime.h>

typedef _Float16 f16;
typedef _Float16 f16x2 __attribute__((ext_vector_type(2)));
typedef _Float16 f16x4 __attribute__((ext_vector_type(4)));
typedef _Float16 f16x8 __attribute__((ext_vector_type(8)));
typedef float    f32x4 __attribute__((ext_vector_type(4)));

static __device__ __forceinline__ float dot4(uint4 w, uint4 h, float acc) {
    acc = __builtin_amdgcn_fdot2(__builtin_bit_cast(f16x2, w.x), __builtin_bit_cast(f16x2, h.x), acc, false);
    acc = __builtin_amdgcn_fdot2(__builtin_bit_cast(f16x2, w.y), __builtin_bit_cast(f16x2, h.y), acc, false);
    acc = __builtin_amdgcn_fdot2(__builtin_bit_cast(f16x2, w.z), __builtin_bit_cast(f16x2, h.z), acc, false);
    acc = __builtin_amdgcn_fdot2(__builtin_bit_cast(f16x2, w.w), __builtin_bit_cast(f16x2, h.w), acc, false);
    return acc;
}

// lane^1 / lane^2 exchange via DPP quad_perm (VALU pipe, no LDS)
static __device__ __forceinline__ float dppx1(float v) {
    int r = __builtin_amdgcn_mov_dpp(__builtin_bit_cast(int, v), 0xB1, 0xF, 0xF, true); // {1,0,3,2}
    return __builtin_bit_cast(float, r);
}
static __device__ __forceinline__ float dppx2(float v) {
    int r = __builtin_amdgcn_mov_dpp(__builtin_bit_cast(int, v), 0x4E, 0xF, 0xF, true); // {2,3,0,1}
    return __builtin_bit_cast(float, r);
}

// ---------------- Phase 0: convert W_ih, W_hh to f16 ----------------
__global__ __launch_bounds__(256) void cvt_w(const float4* __restrict__ wih4,
                                             const float4* __restrict__ whh4,
                                             f16x4* __restrict__ wih16,
                                             f16x4* __restrict__ whh16) {
    int idx = blockIdx.x * 256 + threadIdx.x;   // 98304 total float4s
    if (idx < 32768) {
        float4 v = wih4[idx];
        wih16[idx] = (f16x4){(f16)v.x, (f16)v.y, (f16)v.z, (f16)v.w};
    } else if (idx < 98304) {
        int k = idx - 32768;
        float4 v = whh4[k];
        whh16[k] = (f16x4){(f16)v.x, (f16)v.y, (f16)v.z, (f16)v.w};
    }
}

// ---------------- Phase 1: xp = x @ W_ih^T + (b_ih + b_hh), f16 out ----------------
__global__ __launch_bounds__(256) void gemm_xp(const float* __restrict__ x,
                                               const f16* __restrict__ wih,
                                               const float* __restrict__ bih,
                                               const float* __restrict__ bhh,
                                               f16* __restrict__ xp,
                                               int tc, int t0, int L) {
    __shared__ f16 As[128][48];
    __shared__ f16 Bs[128][48];
    int tid = threadIdx.x;
    int r = tid >> 1, kh = (tid & 1) * 16;

    long mbase = (long)blockIdx.x * 128;
    int jb = blockIdx.y * 128;
    long mp = mbase + r;
    int n = (int)(mp / tc);
    int trel = (int)(mp - (long)n * tc);
    const float* xrow = x + ((long)n * L + t0 + trel) * 256 + kh;
    const f16* wrow = wih + (jb + r) * 256 + kh;

    int w = tid >> 6, l = tid & 63, lr = l & 15, lk = l >> 4;
    int wm = w & 1, wn = w >> 1;

    f32x4 acc[4][4] = {};

    for (int kk = 0; kk < 256; kk += 32) {
        float4 a0 = *(const float4*)(xrow + kk);
        float4 a1 = *(const float4*)(xrow + kk + 4);
        float4 a2 = *(const float4*)(xrow + kk + 8);
        float4 a3 = *(const float4*)(xrow + kk + 12);
        uint4  b0 = *(const uint4*)(wrow + kk);
        uint4  b1 = *(const uint4*)(wrow + kk + 8);
        f16x8 ca = {(f16)a0.x,(f16)a0.y,(f16)a0.z,(f16)a0.w,(f16)a1.x,(f16)a1.y,(f16)a1.z,(f16)a1.w};
        f16x8 cb = {(f16)a2.x,(f16)a2.y,(f16)a2.z,(f16)a2.w,(f16)a3.x,(f16)a3.y,(f16)a3.z,(f16)a3.w};
        __syncthreads();
        *(f16x8*)&As[r][kh]     = ca;
        *(f16x8*)&As[r][kh + 8] = cb;
        *(uint4*)&Bs[r][kh]     = b0;
        *(uint4*)&Bs[r][kh + 8] = b1;
        __syncthreads();

        uint4 af[4], bf[4];
#pragma unroll
        for (int mi = 0; mi < 4; ++mi) af[mi] = *(const uint4*)&As[wm * 64 + mi * 16 + lr][lk * 8];
#pragma unroll
        for (int ni = 0; ni < 4; ++ni) bf[ni] = *(const uint4*)&Bs[wn * 64 + ni * 16 + lr][lk * 8];
#pragma unroll
        for (int mi = 0; mi < 4; ++mi)
#pragma unroll
            for (int ni = 0; ni < 4; ++ni)
                acc[mi][ni] = __builtin_amdgcn_mfma_f32_16x16x32_f16(
                    __builtin_bit_cast(f16x8, af[mi]), __builtin_bit_cast(f16x8, bf[ni]),
                    acc[mi][ni], 0, 0, 0);
    }

#pragma unroll
    for (int ni = 0; ni < 4; ++ni) {
        int j = jb + wn * 64 + ni * 16 + lr;
        float bias = bih[j] + bhh[j];
#pragma unroll
        for (int mi = 0; mi < 4; ++mi) {
            long row = mbase + wm * 64 + mi * 16 + lk * 4;
#pragma unroll
            for (int rr = 0; rr < 4; ++rr)
                xp[(row + rr) * 512 + j] = (f16)(acc[mi][ni][rr] + bias);
        }
    }
}

// ---------------- Phase 2 (+fused phase 3): the recurrence ----------------
// grid = N (128), block = 1024 (16 waves, 4/SIMD). Per-lane W = 512 B:
// 96 VGPRs (3 uint4-chunks x 8 rows) + 1 chunk/row in 128 KB LDS.
// Fits the default 128-VGPR budget -> no allocator fight, no spill.
__global__ __launch_bounds__(1024) void rnn_seq(const f16* __restrict__ whh16,
                                                const f16* __restrict__ xp,
                                                const float* __restrict__ hin,
                                                float* __restrict__ out,
                                                const float* __restrict__ wout,
                                                const float* __restrict__ bout,
                                                int tc, int finalflag, int ytotal) {
    __shared__ uint4 WL[8192];       // 128 KB, slot = tid*8 + (r ^ (tid&7))
    __shared__ uint4 hbuf[2][80];    // stride-5 padded: slot = i*5 + c (2-way banks = free)

    const int tid = threadIdx.x;
    const int n = blockIdx.x;
    const int i  = tid & 15;         // k-group (16 x 32 k)
    const int jg = tid >> 4;         // j-group (64 x 8 rows)
    const int sw = tid & 7;

    // ---- load W_hh: rows jg*8..+7, cols i*32..+31; 3 chunks regs + 1 LDS ----
    uint4 wr[8][3];
    const f16* wbase = whh16 + (long)(jg * 8) * 512 + i * 32;
#pragma unroll
    for (int r = 0; r < 8; ++r) {
        const uint4* p = (const uint4*)(wbase + (long)r * 512);
        wr[r][0] = p[0]; wr[r][1] = p[1]; wr[r][2] = p[2];
        WL[tid * 8 + (r ^ sw)] = p[3];
    }

    // ---- h0 into padded layout ----
    if (tid < 512) {
        int j = tid;
        ((f16*)&hbuf[0][0])[((j >> 5) * 5 + ((j >> 3) & 3)) * 8 + (j & 7)] =
            (f16)hin[n * 512 + j];
    }
    __syncthreads();

    const int jrow = ((i & 1) << 2) | (i & 2) | ((i >> 2) & 1);  // bitrev3(i&7)
    const int jfin = jg * 8 + jrow;                               // pair (i, i^8) duplicates
    const int widx = ((jfin >> 5) * 5 + ((jfin >> 3) & 3)) * 8 + (jfin & 7);
    const f16* xpp = xp + ((long)n * tc) * 512 + jfin;
    const int wbyte = tid * 128 + sw * 16;   // WL byte base; chunk r at (wbyte ^ (r<<4))

    float lasth = 0.f;
    int cur = 0;

    for (int t = 0; t < tc; ++t) {
        float xv = (float)xpp[(long)t * 512];    // global scalar, issued early

        const uint4* hrow = &hbuf[cur][i * 5];
        uint4 hv0 = hrow[0], hv1 = hrow[1], hv2 = hrow[2], hv3 = hrow[3];

        float a[8];
#pragma unroll
        for (int r = 0; r < 8; ++r)
            a[r] = dot4(wr[r][2], hv2, dot4(wr[r][1], hv1, dot4(wr[r][0], hv0, 0.f)));
#pragma unroll
        for (int r = 0; r < 8; ++r) {
            uint4 wl = *(const uint4*)((const char*)WL + (wbyte ^ (r << 4)));
            a[r] = dot4(wl, hv3, a[r]);
        }

        // reduce over 16 k-lanes: xor1,xor2 (DPP), xor4, xor8 (shfl)
#pragma unroll
        for (int s = 0; s < 4; ++s) {
            float lo = a[s], hi = a[s + 4];
            float keep = (i & 1) ? hi : lo, send = (i & 1) ? lo : hi;
            a[s] = keep + dppx1(send);
        }
#pragma unroll
        for (int s = 0; s < 2; ++s) {
            float lo = a[s], hi = a[s + 2];
            float keep = (i & 2) ? hi : lo, send = (i & 2) ? lo : hi;
            a[s] = keep + dppx2(send);
        }
        {
            float lo = a[0], hi = a[1];
            float keep = (i & 4) ? hi : lo, send = (i & 4) ? lo : hi;
            a[0] = keep + __shfl_xor(send, 4);
        }
        a[0] += __shfl_xor(a[0], 8);   // pair-halves sum; both lanes keep same row

        float pre = a[0] + xv;
        pre = fminf(fmaxf(pre, -20.f), 20.f);
        float e = __expf(2.f * pre);
        float hn = 1.f - 2.f / (e + 1.f);       // tanh
        lasth = hn;
        ((f16*)&hbuf[cur ^ 1][0])[widx] = (f16)hn;  // pair writes same value: benign
        __syncthreads();
        cur ^= 1;
    }

    out[ytotal + n * 512 + jfin] = lasth;    // h state (chunk handoff / final h)

    if (finalflag) {
        __syncthreads();
        float* hf = (float*)WL;              // reuse WL: 512 f32
        hf[jfin] = lasth;
        __syncthreads();
        if (tid < 512) {
            int jy = tid;
            float acc = bout[jy];
            const float* wrp = wout + (long)jy * 512;
#pragma unroll 4
            for (int k = 0; k < 512; k += 8) {
                float4 w0 = *(const float4*)(wrp + k);
                float4 w1 = *(const float4*)(wrp + k + 4);
                float4 g0 = *(const float4*)(hf + k);
                float4 g1 = *(const float4*)(hf + k + 4);
                acc = fmaf(w0.x, g0.x, acc); acc = fmaf(w0.y, g0.y, acc);
                acc = fmaf(w0.z, g0.z, acc); acc = fmaf(w0.w, g0.w, acc);
                acc = fmaf(w1.x, g1.x, acc); acc = fmaf(w1.y, g1.y, acc);
                acc = fmaf(w1.z, g1.z, acc); acc = fmaf(w1.w, g1.w, acc);
            }
            out[n * 512 + jy] = acc;         // y
        }
    }
}

extern "C" void kernel_launch(void* const* d_in, const int* in_sizes, int n_in,
                              void* d_out, int out_size, void* d_ws, size_t ws_size,
                              hipStream_t stream) {
    const float* x    = (const float*)d_in[0];
    const float* h0   = (const float*)d_in[1];
    const float* wih  = (const float*)d_in[2];
    const float* whh  = (const float*)d_in[3];
    const float* bih  = (const float*)d_in[4];
    const float* bhh  = (const float*)d_in[5];
    const float* wout = (const float*)d_in[6];
    const float* bout = (const float*)d_in[7];
    float* out = (float*)d_out;

    int N = in_sizes[1] / 512;                      // 128
    int L = (int)((long)in_sizes[0] / ((long)N * 256)); // 1024
    int ytotal = N * 512;

    char* ws = (char*)d_ws;
    f16* whh16 = (f16*)ws;                 // 524288 B
    f16* wih16 = (f16*)(ws + 524288);      // 262144 B
    f16* xp    = (f16*)(ws + 786432);
    long per_t = (long)N * 512 * 2;
    long cap = (ws_size > 786432) ? (long)(ws_size - 786432) : 0;
    long Tc = cap / per_t;
    if (Tc > L) Tc = L;
    if (Tc < 1) Tc = 1;

    cvt_w<<<384, 256, 0, stream>>>((const float4*)wih, (const float4*)whh,
                                   (f16x4*)wih16, (f16x4*)whh16);

    for (int t0 = 0; t0 < L;) {
        int tc = (int)((L - t0 < Tc) ? (L - t0) : Tc);
        gemm_xp<<<dim3(tc, 4), 256, 0, stream>>>(x, wih16, bih, bhh, xp, tc, t0, L);
        const float* hsrc = (t0 == 0) ? h0 : (const float*)(out + ytotal);
        int fin = (t0 + tc == L) ? 1 : 0;
        rnn_seq<<<N, 1024, 0, stream>>>(whh16, xp, hsrc, out, wout, bout, tc, fin, ytotal);
        t0 += tc;
    }
}